// Round 8
// baseline (409.392 us; speedup 1.0000x reference)
//
#include <hip/hip_runtime.h>

// QuantizedBottleneck, single fused kernel + weight-prep.
//   prep : pack MFMA A-fragments (w1/w2/w3 -> i8) + w1 row-sums into d_ws
//   fused: per block = (batch b, 2 output rows r0..r0+1):
//     stage A: conv1 1x1 256->64 on 4-row halo (224 px) -> mid slab (LDS i8)
//     stage B: conv2 3x3 64->64 from padded-col slab -> mid2 (LDS i8)
//     stage C: conv3 1x1 64->256 + bn3 + residual add (LDS LUTs) -> out
// mid holds (q-zin2), mid2 holds (q-zin3): zero-padding == zero bytes.
// Stage A stages (x-128) bytes via v_perm and corrects with (128-zin)*rowsum(w1)
// in the epilogue (exact). Requant via exact single-shift identity:
//   ((p+nudge)>>31 + 2^(s-1)) >> s == (p + nudge + 2^(30+s)) >> (31+s)
// 2-row strips: 38.5 KB LDS -> 4 blocks/CU, 896 blocks all co-resident.
// XCD swizzle: each XCD gets 4 whole batches (halo rows L2-local).
// MFMA 16x16x64_i8: A[m=lane&15][k=(lane>>4)*16+j], B[k][n=lane&15],
// C/D: col=lane&15, row=(lane>>4)*4+reg.   (no nontemporal builtins — R5 lesson)

typedef int v4i __attribute__((ext_vector_type(4)));

#define BATCH 32
#define CIN 256
#define HW 3136
#define W56 56
#define WP_BYTES ((size_t)68 * 64 * 16)

__device__ __forceinline__ int requant_f(int acc, int M0, long long pAdd,
                                         long long nAdd, int tSh, int zout) {
    long long prod = (long long)acc * (long long)M0;
    long long add = (prod >= 0) ? pAdd : nAdd;
    int v = (int)((prod + add) >> tSh) + zout;
    return v < 0 ? 0 : (v > 255 ? 255 : v);
}

// pack low bytes of 4 int32 (each in [0,255]) into one dword
__device__ __forceinline__ unsigned pk4(unsigned x0, unsigned x1,
                                        unsigned x2, unsigned x3) {
#if __has_builtin(__builtin_amdgcn_perm)
    unsigned t01 = __builtin_amdgcn_perm(x1, x0, 0x0400u);   // [x0b0,x1b0,*,*]
    unsigned t23 = __builtin_amdgcn_perm(x3, x2, 0x0400u);   // [x2b0,x3b0,*,*]
    return __builtin_amdgcn_perm(t23, t01, 0x05040100u);
#else
    return (x0 & 255u) | ((x1 & 255u) << 8) | ((x2 & 255u) << 16) | (x3 << 24);
#endif
}

__device__ __forceinline__ v4i pack16f(const float* src, int stride) {
    v4i r;
#pragma unroll
    for (int d = 0; d < 4; ++d) {
        unsigned int u = 0;
#pragma unroll
        for (int by = 0; by < 4; ++by) {
            int v = (int)src[(d * 4 + by) * stride];
            u |= ((unsigned int)(v & 255)) << (8 * by);
        }
        r[d] = (int)u;
    }
    return r;
}

// -------- prep: fragsets w1 [0,16), w2 [16,52), w3 [52,68) + w1 rowsums -----
__global__ __launch_bounds__(256) void k_prep(
    const float* __restrict__ w1, const float* __restrict__ w2,
    const float* __restrict__ w3, v4i* __restrict__ wp, int* __restrict__ rs)
{
    int id = blockIdx.x * 256 + threadIdx.x;
    int fid = id >> 6, lane = id & 63;
    if (fid < 68) {
        int col = lane & 15, ci0 = (lane >> 4) * 16;
        const float* src;
        int stride;
        if (fid < 16) {
            int wv = fid >> 2, ks = fid & 3;
            src = w1 + (size_t)(wv * 16 + col) * 256 + ks * 64 + ci0;
            stride = 1;
        } else if (fid < 52) {
            int i = fid - 16, wv = i / 9, t = i - wv * 9;
            src = w2 + ((size_t)(wv * 16 + col) * 64 + ci0) * 9 + t;
            stride = 9;
        } else {
            int s = fid - 52;
            src = w3 + (size_t)(s * 16 + col) * 64 + ci0;
            stride = 1;
        }
        wp[fid * 64 + lane] = pack16f(src, stride);
    }
    if (id < 64) {                      // w1 row sums for zero-point correction
        int s = 0;
        for (int ci = 0; ci < 256; ++ci) s += (int)w1[id * 256 + ci];
        rs[id] = s;
    }
}

// -------- fused bottleneck: grid (28, 32), block 256 ------------------------
__global__ __launch_bounds__(256, 4) void k_fused(
    const int* __restrict__ x, const v4i* __restrict__ wp,
    const int* __restrict__ rs,
    const float* __restrict__ bn1_w, const float* __restrict__ bn1_b,
    const float* __restrict__ bn2_w, const float* __restrict__ bn2_b,
    const float* __restrict__ bn3_w, const float* __restrict__ bn3_b,
    const int* __restrict__ conv_zin, const int* __restrict__ conv_m0,
    const int* __restrict__ conv_shift, const int* __restrict__ conv_zout,
    const int* __restrict__ bn_m0, const int* __restrict__ bn_shift,
    const int* __restrict__ bn_zout,
    const int* __restrict__ add_z, const int* __restrict__ add_m0,
    const int* __restrict__ add_shift, const int* __restrict__ add_zout,
    int* __restrict__ out)
{
    __shared__ v4i smX[1120];           // stage A: 224 px x 80B; stage C: mid2
    __shared__ v4i smM[1160];           // mid slab: 4 rows x 58 cols x 80B
    __shared__ int lutA[256], lutB[256];

    const int tid = threadIdx.x, lane = tid & 63, wv = tid >> 6;
    const int col = lane & 15, koff = lane >> 4;
    // XCD-locality swizzle: each XCD (lin%8) owns 4 whole batches
    const int lin = blockIdx.y * 28 + blockIdx.x;
    const int wrk = (lin & 7) * 112 + (lin >> 3);
    const int b = wrk / 28, r0 = (wrk - b * 28) * 2;
    const int rowb = koff * 4;
    const int co0 = wv * 16;

    // residual-combine LUTs (one entry per thread)
    {
        const int az0 = add_z[0], az1 = add_z[1];
        const int am0 = add_m0[0], am1 = add_m0[1];
        const int ash0 = add_shift[0], ash1 = add_shift[1];
        const int azout = add_zout[0];
        long long pA = (long long)(tid - az0) * am0;
        long long pB = (long long)(tid - az1) * am1;
        long long P0 = (1LL << 30) + (1LL << (30 + ash0));
        long long N0 = (1LL - (1LL << 30)) + (1LL << (30 + ash0));
        long long P1 = (1LL << 30) + (1LL << (30 + ash1));
        long long N1 = (1LL - (1LL << 30)) + (1LL << (30 + ash1));
        lutA[tid] = (int)((pA + (pA >= 0 ? P0 : N0)) >> (31 + ash0));
        lutB[tid] = (int)((pB + (pB >= 0 ? P1 : N1)) >> (31 + ash1)) + azout;
    }
    // zero mid-slab edge columns 0 and 57 (4 rows x 2 sides x 16 dwords)
    if (tid < 128) {
        int e = tid >> 4, d = tid & 15;
        int row = e >> 1, side = e & 1;
        ((int*)smM)[(row * 58 + side * 57) * 20 + d] = 0;
    }

    const int zin = conv_zin[0];
    v4i a1[4];
#pragma unroll
    for (int ks = 0; ks < 4; ++ks) a1[ks] = wp[(wv * 4 + ks) * 64 + lane];

    // ---------------- stage A: conv1 on 224 halo px, K=256 -----------------
    v4i accA[14];
#pragma unroll
    for (int i = 0; i < 14; ++i) accA[i] = (v4i){0, 0, 0, 0};

    unsigned long long* smuX = (unsigned long long*)smX;
#pragma unroll
    for (int ks = 0; ks < 4; ++ks) {
        if (ks) __syncthreads();           // prior MFMA reads of smX done
#pragma unroll
        for (int u = 0; u < 2; ++u) {
            int unit = tid + u * 256;
            if (unit < 448) {              // 56 px-quads x 8 ci-groups
                int cg = unit & 7, qq = unit >> 3;
                int row = qq / 14, quad = qq - row * 14;
                int grow = r0 - 1 + row;
                if ((unsigned)grow < 56u) {
                    const int* xb = x + (size_t)(b * CIN + ks * 64 + cg * 8) * HW
                                      + grow * W56 + quad * 4;
                    v4i xa[8];
#pragma unroll
                    for (int j = 0; j < 8; ++j)
                        xa[j] = *(const v4i*)(xb + (size_t)j * HW);
#pragma unroll
                    for (int p = 0; p < 4; ++p) {
                        unsigned lo = pk4(xa[0][p], xa[1][p], xa[2][p], xa[3][p])
                                      ^ 0x80808080u;
                        unsigned hi = pk4(xa[4][p], xa[5][p], xa[6][p], xa[7][p])
                                      ^ 0x80808080u;
                        smuX[(qq * 4 + p) * 10 + cg] =
                            ((unsigned long long)hi << 32) | lo;
                    }
                } else {
#pragma unroll
                    for (int p = 0; p < 4; ++p)
                        smuX[(qq * 4 + p) * 10 + cg] = 0ull;  // epilogue zeroes anyway
                }
            }
        }
        __syncthreads();
#pragma unroll
        for (int nt = 0; nt < 14; ++nt) {
            v4i bf = smX[(nt * 16 + col) * 5 + koff];
            accA[nt] = __builtin_amdgcn_mfma_i32_16x16x64_i8(a1[ks], bf, accA[nt], 0, 0, 0);
        }
    }

    // stage A epilogue: zp-correct + requant + bn1 -> (q-zin2) into mid slab
    {
        const int cm0 = conv_m0[0], csh = conv_shift[0], czo = conv_zout[0];
        const int bm0 = bn_m0[0], bsh = bn_shift[0], bzo = bn_zout[0];
        const long long cP = (1LL << 30) + (1LL << (30 + csh));
        const long long cN = (1LL - (1LL << 30)) + (1LL << (30 + csh));
        const long long bP = (1LL << 30) + (1LL << (30 + bsh));
        const long long bN = (1LL - (1LL << 30)) + (1LL << (30 + bsh));
        const int cT = 31 + csh, bT = 31 + bsh;
        const int zin2 = conv_zin[1];
        int bw[4], bb[4], corr[4];
#pragma unroll
        for (int r = 0; r < 4; ++r) {
            bw[r] = (int)bn1_w[co0 + rowb + r];
            bb[r] = (int)bn1_b[co0 + rowb + r];
            corr[r] = (128 - zin) * rs[co0 + rowb + r];
        }
#pragma unroll
        for (int nt = 0; nt < 14; ++nt) {
            int px = nt * 16 + col;
            int row = px / W56, gw = px - row * W56;
            int grow = r0 - 1 + row;
            unsigned int pkd = 0;
            if ((unsigned)grow < 56u) {
#pragma unroll
                for (int r = 0; r < 4; ++r) {
                    int q1 = requant_f(accA[nt][r] + corr[r], cm0, cP, cN, cT, czo);
                    int a2 = (q1 - czo) * bw[r] + bb[r];
                    int q2 = requant_f(a2, bm0, bP, bN, bT, bzo);
                    pkd |= ((unsigned int)((q2 - zin2) & 255)) << (8 * r);
                }
            }
            ((int*)smM)[(row * 58 + 1 + gw) * 20 + wv * 4 + koff] = (int)pkd;
        }
    }
    __syncthreads();

    // ---------------- stage B: conv2 3x3 from mid slab ----------------------
    v4i a2f[9];
#pragma unroll
    for (int t = 0; t < 9; ++t) a2f[t] = wp[(16 + wv * 9 + t) * 64 + lane];

    int basep[7];
#pragma unroll
    for (int nt = 0; nt < 7; ++nt) {
        int pix = nt * 16 + col;
        int orow = pix / W56, wc = pix - orow * W56;
        basep[nt] = (orow * 58 + wc) * 5 + koff;
    }

    v4i accB[7];
#pragma unroll
    for (int i = 0; i < 7; ++i) accB[i] = (v4i){0, 0, 0, 0};
#pragma unroll
    for (int kh = 0; kh < 3; ++kh) {
#pragma unroll
        for (int kw = 0; kw < 3; ++kw) {
            v4i af = a2f[kh * 3 + kw];
            const int toff = (kh * 58 + kw) * 5;
#pragma unroll
            for (int nt = 0; nt < 7; ++nt) {
                v4i bf = smM[basep[nt] + toff];
                accB[nt] = __builtin_amdgcn_mfma_i32_16x16x64_i8(af, bf, accB[nt], 0, 0, 0);
            }
        }
    }

    // stage B epilogue: requant + bn2 -> (q-zin3) into mid2 (smX region)
    {
        const int cm0 = conv_m0[1], csh = conv_shift[1], czo = conv_zout[1];
        const int bm0 = bn_m0[1], bsh = bn_shift[1], bzo = bn_zout[1];
        const long long cP = (1LL << 30) + (1LL << (30 + csh));
        const long long cN = (1LL - (1LL << 30)) + (1LL << (30 + csh));
        const long long bP = (1LL << 30) + (1LL << (30 + bsh));
        const long long bN = (1LL - (1LL << 30)) + (1LL << (30 + bsh));
        const int cT = 31 + csh, bT = 31 + bsh;
        const int zin3 = conv_zin[2];
        int bw[4], bb[4];
#pragma unroll
        for (int r = 0; r < 4; ++r) {
            bw[r] = (int)bn2_w[co0 + rowb + r];
            bb[r] = (int)bn2_b[co0 + rowb + r];
        }
#pragma unroll
        for (int nt = 0; nt < 7; ++nt) {
            unsigned int pkd = 0;
#pragma unroll
            for (int r = 0; r < 4; ++r) {
                int q1 = requant_f(accB[nt][r], cm0, cP, cN, cT, czo);
                int a2 = (q1 - czo) * bw[r] + bb[r];
                int q2 = requant_f(a2, bm0, bP, bN, bT, bzo);
                pkd |= ((unsigned int)((q2 - zin3) & 255)) << (8 * r);
            }
            ((int*)smX)[(nt * 16 + col) * 20 + wv * 4 + koff] = (int)pkd;
        }
    }

    // preload tile-0 residual x before the barrier
    v4i a3f[4];
#pragma unroll
    for (int f = 0; f < 4; ++f) a3f[f] = wp[(52 + wv * 4 + f) * 64 + lane];
    const int ghw0 = r0 * W56;
    int xcur[4][4], xnxt[4][4];
#pragma unroll
    for (int f = 0; f < 4; ++f)
#pragma unroll
        for (int r = 0; r < 4; ++r)
            xcur[f][r] = x[(size_t)(b * CIN + wv * 64 + f * 16 + rowb + r) * HW
                           + ghw0 + col];
    __syncthreads();

    // ---------------- stage C: conv3 1x1 64->256 + bn3 + residual -----------
    {
        const int cm0 = conv_m0[2], csh = conv_shift[2], czo = conv_zout[2];
        const int bm0 = bn_m0[2], bsh = bn_shift[2], bzo = bn_zout[2];
        const long long cP = (1LL << 30) + (1LL << (30 + csh));
        const long long cN = (1LL - (1LL << 30)) + (1LL << (30 + csh));
        const long long bP = (1LL << 30) + (1LL << (30 + bsh));
        const long long bN = (1LL - (1LL << 30)) + (1LL << (30 + bsh));
        const int cT = 31 + csh, bT = 31 + bsh;
        int bw[4][4], bb[4][4];
#pragma unroll
        for (int f = 0; f < 4; ++f)
#pragma unroll
            for (int r = 0; r < 4; ++r) {
                bw[f][r] = (int)bn3_w[wv * 64 + f * 16 + rowb + r];
                bb[f][r] = (int)bn3_b[wv * 64 + f * 16 + rowb + r];
            }
        const v4i zf = (v4i){0, 0, 0, 0};
#pragma unroll
        for (int nt = 0; nt < 7; ++nt) {
            if (nt < 6) {
#pragma unroll
                for (int f = 0; f < 4; ++f)
#pragma unroll
                    for (int r = 0; r < 4; ++r)
                        xnxt[f][r] = x[(size_t)(b * CIN + wv * 64 + f * 16 + rowb + r) * HW
                                       + ghw0 + (nt + 1) * 16 + col];
            }
            v4i bf = smX[(nt * 16 + col) * 5 + koff];
            v4i accC[4];
#pragma unroll
            for (int f = 0; f < 4; ++f)
                accC[f] = __builtin_amdgcn_mfma_i32_16x16x64_i8(a3f[f], bf, zf, 0, 0, 0);
#pragma unroll
            for (int f = 0; f < 4; ++f)
#pragma unroll
                for (int r = 0; r < 4; ++r) {
                    int q1 = requant_f(accC[f][r], cm0, cP, cN, cT, czo);
                    int a2 = (q1 - czo) * bw[f][r] + bb[f][r];
                    int q2 = requant_f(a2, bm0, bP, bN, bT, bzo);
                    int res = lutA[xcur[f][r]] + lutB[q2];
                    res = res < 0 ? 0 : (res > 255 ? 255 : res);
                    out[(size_t)(b * CIN + wv * 64 + f * 16 + rowb + r) * HW
                        + ghw0 + nt * 16 + col] = res;
                }
#pragma unroll
            for (int f = 0; f < 4; ++f)
#pragma unroll
                for (int r = 0; r < 4; ++r) xcur[f][r] = xnxt[f][r];
        }
    }
}

extern "C" void kernel_launch(void* const* d_in, const int* in_sizes, int n_in,
                              void* d_out, int out_size, void* d_ws, size_t ws_size,
                              hipStream_t stream) {
    const int* x = (const int*)d_in[0];
    const float* w1 = (const float*)d_in[1];
    const float* w2 = (const float*)d_in[2];
    const float* w3 = (const float*)d_in[3];
    const float* bn1_w = (const float*)d_in[4];
    const float* bn1_b = (const float*)d_in[5];
    const float* bn2_w = (const float*)d_in[6];
    const float* bn2_b = (const float*)d_in[7];
    const float* bn3_w = (const float*)d_in[8];
    const float* bn3_b = (const float*)d_in[9];
    const int* conv_zin = (const int*)d_in[10];
    const int* conv_m0 = (const int*)d_in[11];
    const int* conv_shift = (const int*)d_in[12];
    const int* conv_zout = (const int*)d_in[13];
    const int* bn_m0 = (const int*)d_in[14];
    const int* bn_shift = (const int*)d_in[15];
    const int* bn_zout = (const int*)d_in[16];
    const int* add_z = (const int*)d_in[17];
    const int* add_m0 = (const int*)d_in[18];
    const int* add_shift = (const int*)d_in[19];
    const int* add_zout = (const int*)d_in[20];

    v4i* wp = (v4i*)d_ws;
    int* rs = (int*)((char*)d_ws + WP_BYTES);

    k_prep<<<dim3(17), dim3(256), 0, stream>>>(w1, w2, w3, wp, rs);
    k_fused<<<dim3(28, 32), dim3(256), 0, stream>>>(x, wp, rs,
        bn1_w, bn1_b, bn2_w, bn2_b, bn3_w, bn3_b,
        conv_zin, conv_m0, conv_shift, conv_zout, bn_m0, bn_shift, bn_zout,
        add_z, add_m0, add_shift, add_zout, (int*)d_out);
}